// Round 1
// baseline (29.451 us; speedup 1.0000x reference)
//
#include <hip/hip_runtime.h>
#include <hip/hip_bf16.h>

// CoarseGrain: avg-pool SCALE=4 over last dim of (128, 4, 65536) fp32.
// out[n,c,l] = mean(x[n,c,4l:4l+4]).  Memory-bound streaming kernel.
//
// Each thread computes 4 outputs (one float4 store) from 4 float4 loads
// (64 B in / 16 B out per thread, fully coalesced).

__global__ __launch_bounds__(256) void CoarseGrain_26474178413228_kernel(
    const float* __restrict__ x, float* __restrict__ out, int n_out4) {
    const float4* __restrict__ in4 = reinterpret_cast<const float4*>(x);
    float4* __restrict__ out4 = reinterpret_cast<float4*>(out);

    int idx = blockIdx.x * blockDim.x + threadIdx.x;
    int stride = gridDim.x * blockDim.x;

    for (int i = idx; i < n_out4; i += stride) {
        float4 a = in4[4 * i + 0];
        float4 b = in4[4 * i + 1];
        float4 c = in4[4 * i + 2];
        float4 d = in4[4 * i + 3];
        float4 r;
        r.x = (a.x + a.y + a.z + a.w) * 0.25f;
        r.y = (b.x + b.y + b.z + b.w) * 0.25f;
        r.z = (c.x + c.y + c.z + c.w) * 0.25f;
        r.w = (d.x + d.y + d.z + d.w) * 0.25f;
        out4[i] = r;
    }
}

extern "C" void kernel_launch(void* const* d_in, const int* in_sizes, int n_in,
                              void* d_out, int out_size, void* d_ws, size_t ws_size,
                              hipStream_t stream) {
    const float* x = (const float*)d_in[0];
    float* out = (float*)d_out;

    // out_size = 128*4*16384 = 8,388,608 (divisible by 4)
    int n_out4 = out_size / 4;

    const int block = 256;
    int grid = (n_out4 + block - 1) / block;
    if (grid > 2048) grid = 2048;  // grid-stride the rest

    CoarseGrain_26474178413228_kernel<<<grid, block, 0, stream>>>(x, out, n_out4);
}